// Round 2
// baseline (2401.208 us; speedup 1.0000x reference)
//
#include <hip/hip_runtime.h>
#include <hip/hip_bf16.h>

#define NFEAT 128

// ---------------- int64-vs-int32 detection + canonicalization ----------------
// If the harness staged the reference's int64 arrays verbatim, every odd
// 32-bit word (little-endian high word) of nonnegative values < 2^31 is 0.
// Sample 256 spread-out odd words from the first half (bounds-safe under both
// interpretations); all-zero => int64.

__global__ __launch_bounds__(256) void k_detect(const int* __restrict__ p, int nElem,
                                                int* __restrict__ flag) {
    __shared__ int any;
    int t = threadIdx.x;
    if (t == 0) any = 0;
    __syncthreads();
    long long stride = (long long)nElem / 512;
    if (stride < 1) stride = 1;
    long long pos = 2 * ((long long)t * stride) + 1;
    if (pos < nElem && p[pos] != 0) atomicOr(&any, 1);
    __syncthreads();
    if (t == 0) *flag = any ? 0 : 1;
}

__global__ __launch_bounds__(256) void k_cvt(const void* __restrict__ src, int* __restrict__ dst,
                                             int n, const int* __restrict__ flag) {
    int i = blockIdx.x * 256 + threadIdx.x;
    if (i < n) {
        if (*flag)
            dst[i] = (int)((const long long*)src)[i];
        else
            dst[i] = ((const int*)src)[i];
    }
}

// ---------------- CSR build ----------------

__global__ __launch_bounds__(256) void k_init_cnt(int* __restrict__ cnt, int N) {
    int i = blockIdx.x * 256 + threadIdx.x;
    if (i < N) cnt[i] = 1;  // self-loop
}

__global__ __launch_bounds__(256) void k_count(const int* __restrict__ col, int* __restrict__ cnt, int E) {
    int e = blockIdx.x * 256 + threadIdx.x;
    if (e < E) atomicAdd(&cnt[col[e]], 1);
}

__global__ __launch_bounds__(256) void k_scan1(const int* __restrict__ cnt, int* __restrict__ pre,
                                               int* __restrict__ bsum, int N) {
    __shared__ int s[256];
    int tid = threadIdx.x;
    int gid = blockIdx.x * 256 + tid;
    int v = (gid < N) ? cnt[gid] : 0;
    s[tid] = v;
    __syncthreads();
    for (int off = 1; off < 256; off <<= 1) {
        int t = (tid >= off) ? s[tid - off] : 0;
        __syncthreads();
        s[tid] += t;
        __syncthreads();
    }
    if (gid < N) pre[gid] = s[tid] - v;  // exclusive within block
    if (tid == 255) bsum[blockIdx.x] = s[255];
}

__global__ __launch_bounds__(256) void k_scan2(int* __restrict__ bsum, int NB) {
    __shared__ int s[256];
    int tid = threadIdx.x;
    int v = (tid < NB) ? bsum[tid] : 0;
    s[tid] = v;
    __syncthreads();
    for (int off = 1; off < 256; off <<= 1) {
        int t = (tid >= off) ? s[tid - off] : 0;
        __syncthreads();
        s[tid] += t;
        __syncthreads();
    }
    if (tid < NB) bsum[tid] = s[tid] - v;  // exclusive block offsets
}

__global__ __launch_bounds__(256) void k_scan3(const int* __restrict__ cnt, const int* __restrict__ pre,
                                               const int* __restrict__ bsum, int* __restrict__ row_ptr,
                                               int* __restrict__ cursor, float* __restrict__ dinv,
                                               int N, int total) {
    int i = blockIdx.x * 256 + threadIdx.x;
    if (i < N) {
        int base = pre[i] + bsum[blockIdx.x];
        row_ptr[i] = base;
        cursor[i] = base;
        dinv[i] = rsqrtf((float)cnt[i]);  // deg >= 1 always (self-loop)
    }
    if (i == 0) row_ptr[N] = total;
}

__global__ __launch_bounds__(256) void k_fill(const int* __restrict__ eidx, const float* __restrict__ dinv,
                                              int* __restrict__ cursor, int2* __restrict__ csr,
                                              int E, int N) {
    int t = blockIdx.x * 256 + threadIdx.x;
    if (t < E) {
        int src = eidx[t];
        int dst = eidx[E + t];
        int pos = atomicAdd(&cursor[dst], 1);
        float nrm = dinv[src] * dinv[dst];
        csr[pos] = make_int2(src, __float_as_int(nrm));
    } else if (t < E + N) {
        int i = t - E;
        int pos = atomicAdd(&cursor[i], 1);
        float d = dinv[i];
        csr[pos] = make_int2(i, __float_as_int(d * d));
    }
}

// ---------------- fp32 GEMM: C[M,128] = A[M,128] @ W[128,128] ----------------
// block = 256 threads: tx = col-quad (32), ty = row-group (8); 32 rows/block,
// each thread computes 4 rows x 4 cols. W fully staged in LDS (64 KB).

__global__ __launch_bounds__(256) void k_gemm(const float* __restrict__ A, const float* __restrict__ W,
                                              float* __restrict__ C, int M) {
    __shared__ float Wl[NFEAT * NFEAT];
    int tid = threadIdx.x;
    const float4* W4 = (const float4*)W;
    float4* Wl4 = (float4*)Wl;
#pragma unroll
    for (int i = 0; i < 16; ++i) Wl4[tid + 256 * i] = W4[tid + 256 * i];
    __syncthreads();

    int tx = tid & 31;
    int ty = tid >> 5;
    int r0 = blockIdx.x * 32 + ty * 4;
    int c0 = tx * 4;
    if (r0 >= M) return;

    float acc[4][4] = {};
    const float4* A4 = (const float4*)A;
    for (int kq = 0; kq < 32; ++kq) {
        float4 hv[4];
#pragma unroll
        for (int i = 0; i < 4; ++i) {
            int r = r0 + i;
            hv[i] = (r < M) ? A4[r * 32 + kq] : make_float4(0.f, 0.f, 0.f, 0.f);
        }
#pragma unroll
        for (int kk = 0; kk < 4; ++kk) {
            int k = kq * 4 + kk;
            float4 w = *(const float4*)&Wl[k * NFEAT + c0];
#pragma unroll
            for (int i = 0; i < 4; ++i) {
                float a = (kk == 0) ? hv[i].x : (kk == 1) ? hv[i].y : (kk == 2) ? hv[i].z : hv[i].w;
                acc[i][0] = fmaf(a, w.x, acc[i][0]);
                acc[i][1] = fmaf(a, w.y, acc[i][1]);
                acc[i][2] = fmaf(a, w.z, acc[i][2]);
                acc[i][3] = fmaf(a, w.w, acc[i][3]);
            }
        }
    }
#pragma unroll
    for (int i = 0; i < 4; ++i) {
        int r = r0 + i;
        if (r < M) {
            float4 o = make_float4(acc[i][0], acc[i][1], acc[i][2], acc[i][3]);
            *(float4*)&C[r * NFEAT + c0] = o;
        }
    }
}

// ---------------- gather aggregation: wave per destination node ----------------

__global__ __launch_bounds__(256) void k_aggregate(const float* __restrict__ hw, const int2* __restrict__ csr,
                                                   const int* __restrict__ row_ptr, const float* __restrict__ bias,
                                                   float* __restrict__ hout, int N) {
    int wid = (blockIdx.x * 256 + threadIdx.x) >> 6;
    int lane = threadIdx.x & 63;
    if (wid >= N) return;
    int beg = row_ptr[wid];
    int end = row_ptr[wid + 1];
    float a0 = 0.f, a1 = 0.f;
    for (int e = beg; e < end; ++e) {
        int2 me = csr[e];
        float nrm = __int_as_float(me.y);
        const float* hrow = hw + (size_t)me.x * NFEAT;
        a0 = fmaf(nrm, hrow[lane], a0);
        a1 = fmaf(nrm, hrow[64 + lane], a1);
    }
    a0 += bias[lane];
    a1 += bias[64 + lane];
    hout[wid * NFEAT + lane] = fmaxf(a0, 0.f);
    hout[wid * NFEAT + 64 + lane] = fmaxf(a1, 0.f);
}

// ---------------- pooling: block per graph (batch is sorted) ----------------

__global__ __launch_bounds__(128) void k_pool(const float* __restrict__ h, const int* __restrict__ batch,
                                              float* __restrict__ pooled, int N) {
    int g = blockIdx.x;
    int t = threadIdx.x;
    int lo = 0, hi = N;
    while (lo < hi) { int mid = (lo + hi) >> 1; if (batch[mid] < g) lo = mid + 1; else hi = mid; }
    int s = lo;
    hi = N;
    while (lo < hi) { int mid = (lo + hi) >> 1; if (batch[mid] < g + 1) lo = mid + 1; else hi = mid; }
    int e = lo;
    float acc = 0.f;
    for (int n = s; n < e; ++n) acc += h[n * NFEAT + t];
    pooled[g * NFEAT + t] = acc;
}

// ---------------- head: out[g,c] = pooled[g,:] @ W_out[:,c] + b_out[c] ----------------
// Output dtype is FLOAT32 (reference returns fp32).

__global__ __launch_bounds__(64) void k_head(const float* __restrict__ pooled, const float* __restrict__ Wout,
                                             const float* __restrict__ bout, float* __restrict__ out) {
    int g = blockIdx.x;
    int l = threadIdx.x;
    float p0 = pooled[g * NFEAT + l];
    float p1 = pooled[g * NFEAT + 64 + l];
#pragma unroll
    for (int c = 0; c < 10; ++c) {
        float v = fmaf(p0, Wout[l * 10 + c], p1 * Wout[(64 + l) * 10 + c]);
#pragma unroll
        for (int off = 32; off > 0; off >>= 1) v += __shfl_down(v, off);
        if (l == 0) out[g * 10 + c] = v + bout[c];
    }
}

// ---------------- launch ----------------

extern "C" void kernel_launch(void* const* d_in, const int* in_sizes, int n_in,
                              void* d_out, int out_size, void* d_ws, size_t ws_size,
                              hipStream_t stream) {
    const float* x        = (const float*)d_in[0];
    const void*  eidx_raw = d_in[1];
    const void*  batch_raw= d_in[2];
    const float* W        = (const float*)d_in[3];
    const float* bias     = (const float*)d_in[4];
    const float* Wout     = (const float*)d_in[5];
    const float* bout     = (const float*)d_in[6];

    int N = in_sizes[0] / NFEAT;   // 50000
    int E = in_sizes[1] / 2;       // 800000
    int NG = out_size / 10;        // 512

    char* ws = (char*)d_ws;
    auto alloc = [&](size_t bytes) {
        char* p = ws;
        ws += (bytes + 255) & ~(size_t)255;
        return p;
    };
    float* hw      = (float*)alloc((size_t)N * NFEAT * 4);
    float* hbuf    = (float*)alloc((size_t)N * NFEAT * 4);
    int2*  csr     = (int2*)alloc((size_t)(E + N) * 8);
    int*   cnt     = (int*)alloc((size_t)N * 4);
    int*   pre     = (int*)alloc((size_t)N * 4);
    int*   bsum    = (int*)alloc(1024);
    int*   row_ptr = (int*)alloc((size_t)(N + 1) * 4);
    int*   cursor  = (int*)alloc((size_t)N * 4);
    float* dinv    = (float*)alloc((size_t)N * 4);
    float* pooled  = (float*)alloc((size_t)NG * NFEAT * 4);
    int*   eidx32  = (int*)alloc((size_t)2 * E * 4);
    int*   batch32 = (int*)alloc((size_t)N * 4);
    int*   flags   = (int*)alloc(256);

    // canonicalize possibly-int64 index inputs to int32
    k_detect<<<1, 256, 0, stream>>>((const int*)eidx_raw, 2 * E, &flags[0]);
    k_detect<<<1, 256, 0, stream>>>((const int*)batch_raw, N, &flags[1]);
    k_cvt<<<(2 * E + 255) / 256, 256, 0, stream>>>(eidx_raw, eidx32, 2 * E, &flags[0]);
    k_cvt<<<(N + 255) / 256, 256, 0, stream>>>(batch_raw, batch32, N, &flags[1]);

    int nbN = (N + 255) / 256;  // 196 <= 256 so scan2 single block works

    k_init_cnt<<<nbN, 256, 0, stream>>>(cnt, N);
    k_count<<<(E + 255) / 256, 256, 0, stream>>>(eidx32 + E, cnt, E);
    k_scan1<<<nbN, 256, 0, stream>>>(cnt, pre, bsum, N);
    k_scan2<<<1, 256, 0, stream>>>(bsum, nbN);
    k_scan3<<<nbN, 256, 0, stream>>>(cnt, pre, bsum, row_ptr, cursor, dinv, N, E + N);
    k_fill<<<(E + N + 255) / 256, 256, 0, stream>>>(eidx32, dinv, cursor, csr, E, N);

    for (int l = 0; l < 3; ++l) {
        const float* hin = (l == 0) ? x : hbuf;
        k_gemm<<<(N + 31) / 32, 256, 0, stream>>>(hin, W + (size_t)l * NFEAT * NFEAT, hw, N);
        k_aggregate<<<(N * 64 + 255) / 256, 256, 0, stream>>>(hw, csr, row_ptr, bias + (size_t)l * NFEAT, hbuf, N);
    }

    k_pool<<<NG, 128, 0, stream>>>(hbuf, batch32, pooled, N);
    k_head<<<NG, 64, 0, stream>>>(pooled, Wout, bout, (float*)d_out);
}

// Round 3
// 564.440 us; speedup vs baseline: 4.2541x; 4.2541x over previous
//
#include <hip/hip_runtime.h>
#include <hip/hip_bf16.h>

#define NFEAT 128

// ---------------- int64-vs-int32 detection + canonicalization ----------------

__global__ __launch_bounds__(256) void k_detect(const int* __restrict__ p, int nElem,
                                                int* __restrict__ flag) {
    __shared__ int any;
    int t = threadIdx.x;
    if (t == 0) any = 0;
    __syncthreads();
    long long stride = (long long)nElem / 512;
    if (stride < 1) stride = 1;
    long long pos = 2 * ((long long)t * stride) + 1;
    if (pos < nElem && p[pos] != 0) atomicOr(&any, 1);
    __syncthreads();
    if (t == 0) *flag = any ? 0 : 1;
}

__global__ __launch_bounds__(256) void k_cvt(const void* __restrict__ src, int* __restrict__ dst,
                                             int n, const int* __restrict__ flag) {
    int i = blockIdx.x * 256 + threadIdx.x;
    if (i < n) {
        if (*flag)
            dst[i] = (int)((const long long*)src)[i];
        else
            dst[i] = ((const int*)src)[i];
    }
}

// ---------------- CSR build ----------------

__global__ __launch_bounds__(256) void k_init_cnt(int* __restrict__ cnt, int N) {
    int i = blockIdx.x * 256 + threadIdx.x;
    if (i < N) cnt[i] = 1;  // self-loop
}

__global__ __launch_bounds__(256) void k_count(const int* __restrict__ col, int* __restrict__ cnt, int E) {
    int e = blockIdx.x * 256 + threadIdx.x;
    if (e < E) atomicAdd(&cnt[col[e]], 1);
}

__global__ __launch_bounds__(256) void k_scan1(const int* __restrict__ cnt, int* __restrict__ pre,
                                               int* __restrict__ bsum, int N) {
    __shared__ int s[256];
    int tid = threadIdx.x;
    int gid = blockIdx.x * 256 + tid;
    int v = (gid < N) ? cnt[gid] : 0;
    s[tid] = v;
    __syncthreads();
    for (int off = 1; off < 256; off <<= 1) {
        int t = (tid >= off) ? s[tid - off] : 0;
        __syncthreads();
        s[tid] += t;
        __syncthreads();
    }
    if (gid < N) pre[gid] = s[tid] - v;  // exclusive within block
    if (tid == 255) bsum[blockIdx.x] = s[255];
}

__global__ __launch_bounds__(256) void k_scan2(int* __restrict__ bsum, int NB) {
    __shared__ int s[256];
    int tid = threadIdx.x;
    int v = (tid < NB) ? bsum[tid] : 0;
    s[tid] = v;
    __syncthreads();
    for (int off = 1; off < 256; off <<= 1) {
        int t = (tid >= off) ? s[tid - off] : 0;
        __syncthreads();
        s[tid] += t;
        __syncthreads();
    }
    if (tid < NB) bsum[tid] = s[tid] - v;  // exclusive block offsets
}

__global__ __launch_bounds__(256) void k_scan3(const int* __restrict__ cnt, const int* __restrict__ pre,
                                               const int* __restrict__ bsum, int* __restrict__ row_ptr,
                                               int* __restrict__ cursor, float* __restrict__ dinv,
                                               int N, int total) {
    int i = blockIdx.x * 256 + threadIdx.x;
    if (i < N) {
        int base = pre[i] + bsum[blockIdx.x];
        row_ptr[i] = base;
        cursor[i] = base;
        dinv[i] = rsqrtf((float)cnt[i]);  // deg >= 1 always (self-loop)
    }
    if (i == 0) row_ptr[N] = total;
}

__global__ __launch_bounds__(256) void k_fill(const int* __restrict__ eidx, const float* __restrict__ dinv,
                                              int* __restrict__ cursor, int2* __restrict__ csr,
                                              int E, int N) {
    int t = blockIdx.x * 256 + threadIdx.x;
    if (t < E) {
        int src = eidx[t];
        int dst = eidx[E + t];
        int pos = atomicAdd(&cursor[dst], 1);
        float nrm = dinv[src] * dinv[dst];
        csr[pos] = make_int2(src, __float_as_int(nrm));
    } else if (t < E + N) {
        int i = t - E;
        int pos = atomicAdd(&cursor[i], 1);
        float d = dinv[i];
        csr[pos] = make_int2(i, __float_as_int(d * d));
    }
}

// ---------------- fp32 GEMM: C[M,128] = A[M,128] @ W[128,128] ----------------
// K-tiled rewrite (v2). 256 threads, tile 64 rows x 128 cols, K in 4 steps of 32.
// A staged TRANSPOSED in LDS (AT[k][row], 8 KB) so frag reads are float4 and
// conflict-free; W staged per K-step (Wld[32][128], 16 KB). Thread (tx,ty):
// tx=tid&15 -> cols {tx*4..+3} and {64+tx*4..+3} (2-way bank alias = free),
// ty=tid>>4 -> rows ty*4..+3. 32 acc regs/thread; ~80 VGPR, 24 KB LDS.
// v1 spilled: compiler fully unrolled kq, VGPR=256, 897 MB scratch writes.

__global__ __launch_bounds__(256) void k_gemm(const float* __restrict__ A, const float* __restrict__ W,
                                              float* __restrict__ C, int M) {
    __shared__ float AT[32 * 64];    // [k][row]
    __shared__ float Wld[32 * 128];  // [k][col]
    int tid = threadIdx.x;
    int tx = tid & 15;
    int ty = tid >> 4;
    int row0 = blockIdx.x * 64;
    const float4* A4 = (const float4*)A;
    const float4* W4 = (const float4*)W;

    float acc[4][8] = {};
    int srow = tid >> 2;       // 0..63: staging row
    int q0 = 2 * (tid & 3);    // 0,2,4,6: float4 pair within the 8-float4 K-chunk
    bool rv = (row0 + srow) < M;
    size_t abase = (size_t)(row0 + srow) * 32;

#pragma unroll 1
    for (int s = 0; s < 4; ++s) {
        __syncthreads();  // previous iteration's LDS reads done
        float4 va = rv ? A4[abase + s * 8 + q0]     : make_float4(0.f, 0.f, 0.f, 0.f);
        float4 vb = rv ? A4[abase + s * 8 + q0 + 1] : make_float4(0.f, 0.f, 0.f, 0.f);
        AT[(q0 * 4 + 0) * 64 + srow] = va.x;
        AT[(q0 * 4 + 1) * 64 + srow] = va.y;
        AT[(q0 * 4 + 2) * 64 + srow] = va.z;
        AT[(q0 * 4 + 3) * 64 + srow] = va.w;
        AT[(q0 * 4 + 4) * 64 + srow] = vb.x;
        AT[(q0 * 4 + 5) * 64 + srow] = vb.y;
        AT[(q0 * 4 + 6) * 64 + srow] = vb.z;
        AT[(q0 * 4 + 7) * 64 + srow] = vb.w;
#pragma unroll
        for (int i = 0; i < 4; ++i) {
            int idx = tid + 256 * i;  // 1024 float4s = W[32][128] tile
            ((float4*)Wld)[idx] = W4[(size_t)(s * 32 + (idx >> 5)) * 32 + (idx & 31)];
        }
        __syncthreads();
#pragma unroll 4
        for (int kk = 0; kk < 32; ++kk) {
            float4 a  = *(const float4*)&AT[kk * 64 + ty * 4];
            float4 w0 = *(const float4*)&Wld[kk * 128 + tx * 4];
            float4 w1 = *(const float4*)&Wld[kk * 128 + 64 + tx * 4];
            float av[4] = {a.x, a.y, a.z, a.w};
            float wv[8] = {w0.x, w0.y, w0.z, w0.w, w1.x, w1.y, w1.z, w1.w};
#pragma unroll
            for (int i = 0; i < 4; ++i)
#pragma unroll
                for (int j = 0; j < 8; ++j)
                    acc[i][j] = fmaf(av[i], wv[j], acc[i][j]);
        }
    }
#pragma unroll
    for (int i = 0; i < 4; ++i) {
        int r = row0 + ty * 4 + i;
        if (r < M) {
            *(float4*)&C[(size_t)r * NFEAT + tx * 4] =
                make_float4(acc[i][0], acc[i][1], acc[i][2], acc[i][3]);
            *(float4*)&C[(size_t)r * NFEAT + 64 + tx * 4] =
                make_float4(acc[i][4], acc[i][5], acc[i][6], acc[i][7]);
        }
    }
}

// ---------------- gather aggregation: wave per destination node ----------------

__global__ __launch_bounds__(256) void k_aggregate(const float* __restrict__ hw, const int2* __restrict__ csr,
                                                   const int* __restrict__ row_ptr, const float* __restrict__ bias,
                                                   float* __restrict__ hout, int N) {
    int wid = (blockIdx.x * 256 + threadIdx.x) >> 6;
    int lane = threadIdx.x & 63;
    if (wid >= N) return;
    int beg = row_ptr[wid];
    int end = row_ptr[wid + 1];
    float a0 = 0.f, a1 = 0.f;
    for (int e = beg; e < end; ++e) {
        int2 me = csr[e];
        float nrm = __int_as_float(me.y);
        const float* hrow = hw + (size_t)me.x * NFEAT;
        a0 = fmaf(nrm, hrow[lane], a0);
        a1 = fmaf(nrm, hrow[64 + lane], a1);
    }
    a0 += bias[lane];
    a1 += bias[64 + lane];
    hout[wid * NFEAT + lane] = fmaxf(a0, 0.f);
    hout[wid * NFEAT + 64 + lane] = fmaxf(a1, 0.f);
}

// ---------------- pooling: block per graph (batch is sorted) ----------------

__global__ __launch_bounds__(128) void k_pool(const float* __restrict__ h, const int* __restrict__ batch,
                                              float* __restrict__ pooled, int N) {
    int g = blockIdx.x;
    int t = threadIdx.x;
    int lo = 0, hi = N;
    while (lo < hi) { int mid = (lo + hi) >> 1; if (batch[mid] < g) lo = mid + 1; else hi = mid; }
    int s = lo;
    hi = N;
    while (lo < hi) { int mid = (lo + hi) >> 1; if (batch[mid] < g + 1) lo = mid + 1; else hi = mid; }
    int e = lo;
    float acc = 0.f;
    for (int n = s; n < e; ++n) acc += h[n * NFEAT + t];
    pooled[g * NFEAT + t] = acc;
}

// ---------------- head: out[g,c] = pooled[g,:] @ W_out[:,c] + b_out[c] ----------------

__global__ __launch_bounds__(64) void k_head(const float* __restrict__ pooled, const float* __restrict__ Wout,
                                             const float* __restrict__ bout, float* __restrict__ out) {
    int g = blockIdx.x;
    int l = threadIdx.x;
    float p0 = pooled[g * NFEAT + l];
    float p1 = pooled[g * NFEAT + 64 + l];
#pragma unroll
    for (int c = 0; c < 10; ++c) {
        float v = fmaf(p0, Wout[l * 10 + c], p1 * Wout[(64 + l) * 10 + c]);
#pragma unroll
        for (int off = 32; off > 0; off >>= 1) v += __shfl_down(v, off);
        if (l == 0) out[g * 10 + c] = v + bout[c];
    }
}

// ---------------- launch ----------------

extern "C" void kernel_launch(void* const* d_in, const int* in_sizes, int n_in,
                              void* d_out, int out_size, void* d_ws, size_t ws_size,
                              hipStream_t stream) {
    const float* x         = (const float*)d_in[0];
    const void*  eidx_raw  = d_in[1];
    const void*  batch_raw = d_in[2];
    const float* W         = (const float*)d_in[3];
    const float* bias      = (const float*)d_in[4];
    const float* Wout      = (const float*)d_in[5];
    const float* bout      = (const float*)d_in[6];

    int N = in_sizes[0] / NFEAT;   // 50000
    int E = in_sizes[1] / 2;       // 800000
    int NG = out_size / 10;        // 512

    char* ws = (char*)d_ws;
    auto alloc = [&](size_t bytes) {
        char* p = ws;
        ws += (bytes + 255) & ~(size_t)255;
        return p;
    };
    float* hw      = (float*)alloc((size_t)N * NFEAT * 4);
    float* hbuf    = (float*)alloc((size_t)N * NFEAT * 4);
    int2*  csr     = (int2*)alloc((size_t)(E + N) * 8);
    int*   cnt     = (int*)alloc((size_t)N * 4);
    int*   pre     = (int*)alloc((size_t)N * 4);
    int*   bsum    = (int*)alloc(1024);
    int*   row_ptr = (int*)alloc((size_t)(N + 1) * 4);
    int*   cursor  = (int*)alloc((size_t)N * 4);
    float* dinv    = (float*)alloc((size_t)N * 4);
    float* pooled  = (float*)alloc((size_t)NG * NFEAT * 4);
    int*   eidx32  = (int*)alloc((size_t)2 * E * 4);
    int*   batch32 = (int*)alloc((size_t)N * 4);
    int*   flags   = (int*)alloc(256);

    // canonicalize possibly-int64 index inputs to int32
    k_detect<<<1, 256, 0, stream>>>((const int*)eidx_raw, 2 * E, &flags[0]);
    k_detect<<<1, 256, 0, stream>>>((const int*)batch_raw, N, &flags[1]);
    k_cvt<<<(2 * E + 255) / 256, 256, 0, stream>>>(eidx_raw, eidx32, 2 * E, &flags[0]);
    k_cvt<<<(N + 255) / 256, 256, 0, stream>>>(batch_raw, batch32, N, &flags[1]);

    int nbN = (N + 255) / 256;  // 196 <= 256 so scan2 single block works

    k_init_cnt<<<nbN, 256, 0, stream>>>(cnt, N);
    k_count<<<(E + 255) / 256, 256, 0, stream>>>(eidx32 + E, cnt, E);
    k_scan1<<<nbN, 256, 0, stream>>>(cnt, pre, bsum, N);
    k_scan2<<<1, 256, 0, stream>>>(bsum, nbN);
    k_scan3<<<nbN, 256, 0, stream>>>(cnt, pre, bsum, row_ptr, cursor, dinv, N, E + N);
    k_fill<<<(E + N + 255) / 256, 256, 0, stream>>>(eidx32, dinv, cursor, csr, E, N);

    for (int l = 0; l < 3; ++l) {
        const float* hin = (l == 0) ? x : hbuf;
        k_gemm<<<(N + 63) / 64, 256, 0, stream>>>(hin, W + (size_t)l * NFEAT * NFEAT, hw, N);
        k_aggregate<<<(N * 64 + 255) / 256, 256, 0, stream>>>(hw, csr, row_ptr, bias + (size_t)l * NFEAT, hbuf, N);
    }

    k_pool<<<NG, 128, 0, stream>>>(hbuf, batch32, pooled, N);
    k_head<<<NG, 64, 0, stream>>>(pooled, Wout, bout, (float*)d_out);
}